// Round 8
// baseline (8388.540 us; speedup 1.0000x reference)
//
#include <hip/hip_runtime.h>
#include <math.h>

typedef unsigned short u16;
typedef unsigned long long u64;
typedef unsigned short us8 __attribute__((ext_vector_type(8)));
typedef short bf16x8 __attribute__((ext_vector_type(8)));
typedef float f32x4 __attribute__((ext_vector_type(4)));

#define D       512
#define SEQ     2048
#define VOCAB   32000
#define NB      16      // scan blocks
#define RPB     32      // rows per block (512/16)
#define STPB    512     // scan threads per block

__device__ __forceinline__ u16 f2bf(float f) {   // round-to-nearest-even
    union { float f; unsigned i; } x; x.f = f;
    unsigned r = x.i + 0x7fff + ((x.i >> 16) & 1);
    return (u16)(r >> 16);
}

// tagged-value exchange: one 8B atom = (step_tag << 32) | f32 bits.
// relaxed agent-scope => LLC-coherent, no cache maintenance; tag+value are
// single-copy atomic so the poll hit IS the data read.
__device__ __forceinline__ u64 tag_ld(const u64* p) {
    return __hip_atomic_load(p, __ATOMIC_RELAXED, __HIP_MEMORY_SCOPE_AGENT);
}
__device__ __forceinline__ void tag_st(u64* p, u64 v) {
    __hip_atomic_store(p, v, __ATOMIC_RELAXED, __HIP_MEMORY_SCOPE_AGENT);
}
__device__ __forceinline__ u64 packtv(float f, unsigned tag) {
    union { float f; unsigned i; } x; x.f = f;
    return ((u64)tag << 32) | (u64)x.i;
}
__device__ __forceinline__ float unpackv(u64 v) {
    union { unsigned i; float f; } x; x.i = (unsigned)v;
    return x.f;
}
// fast tanh: 1 - 2/(1+e^{2x}); exact at +-inf, ~1e-6 rel err
__device__ __forceinline__ float ftanh(float x) {
    return 1.f - 2.f / (1.f + __expf(2.f * x));
}

// ---------------------------------------------------------------------------
// zero the exchange buffers (tag 0 == h0 = 0.0f); runs every call/replay.
// ---------------------------------------------------------------------------
__global__ void init_scratch(u64* __restrict__ hbuf, u64* __restrict__ rhbuf)
{
    const int t = threadIdx.x;            // 512 threads, 1 block
    hbuf[t]  = 0ull;                      // value 0.0f, tag 0  (= h0, step-0 input)
    rhbuf[t] = 0ull;
}

// ---------------------------------------------------------------------------
// Persistent GRU scan: 16 blocks x 512 threads, 2 barriers/step.
// Double-buffered LDS staging (hsmA = h, hsmB = r*h) lets every LLC/HBM
// store-ack drain UNDER the next poll loop instead of at a barrier.
//   phase A: poll hbuf tags>=t -> hsmA; bar1; z,r; issue rhbuf tag t+1
//   phase B: poll rhbuf tags>=t+1 -> hsmB; bar2; hxh,h_new; issue hbuf/outH
// Reuse safety: bar2 separates A-compute(hsmA reads) from next A-stage
// writes; bar1 separates B-compute(hsmB reads) from next B-stage writes.
// Cross-block safety: a tag t+1 atom proves its block finished staging
// (stage-barrier precedes compute), so overwrite-before-read is impossible.
// ---------------------------------------------------------------------------
__global__ __launch_bounds__(STPB, 2) void scan_kernel(
    const int* __restrict__ X,
    const float* __restrict__ WZ, const float* __restrict__ UZ,
    const float* __restrict__ W,  const float* __restrict__ U,
    const float* __restrict__ WR, const float* __restrict__ UR,
    const float* __restrict__ BZ, const float* __restrict__ BR,
    const float* __restrict__ BH,
    u64* __restrict__ hbuf, u64* __restrict__ rhbuf,
    float* __restrict__ outH)
{
    __shared__ int   idxsm[SEQ];
    __shared__ float hsmA[(D / 32) * 33];   // padded staging of h
    __shared__ float hsmB[(D / 32) * 33];   // padded staging of r*h

    const int tid = threadIdx.x, b = blockIdx.x;
    const int r  = tid >> 4;          // 0..31 local row
    const int cg = tid & 15;          // 0..15 column group
    const int c0 = cg * 32;
    const int g  = b * RPB + r;       // global row 0..511

    for (int i = tid; i < SEQ; i += STPB) idxsm[i] = X[i];

    // load weight slices (f32): 3 x 32 = 96 VGPRs
    float uzw[32], urw[32], uw[32];
#pragma unroll
    for (int j = 0; j < 32; j += 4) {
        f32x4 vz = *(const f32x4*)&UZ[(size_t)g * D + c0 + j];
        f32x4 vr = *(const f32x4*)&UR[(size_t)g * D + c0 + j];
        f32x4 vu = *(const f32x4*)&U [(size_t)g * D + c0 + j];
#pragma unroll
        for (int q = 0; q < 4; ++q) {
            uzw[j + q] = vz[q];
            urw[j + q] = vr[q];
            uw [j + q] = vu[q];
        }
    }
    const float bzv = BZ[g], brv = BR[g], bhv = BH[g];
    __syncthreads();

    // embedding pipeline: current-step values in regs, prefetch next
    const int i0 = idxsm[0];
    float ezc = WZ[(size_t)i0 * D + g];
    float erc = WR[(size_t)i0 * D + g];
    float ehc = W [(size_t)i0 * D + g];

#pragma unroll 1
    for (int t = 0; t < SEQ; ++t) {
        const int tn = (t + 1 < SEQ) ? t + 1 : t;
        const int in_ = idxsm[tn];
        const float pz = WZ[(size_t)in_ * D + g];
        const float pr = WR[(size_t)in_ * D + g];
        const float ph = W [(size_t)in_ * D + g];
        const unsigned ta = (unsigned)t;       // hbuf tag for this step's input
        const unsigned tb = (unsigned)t + 1u;  // rhbuf tag for this step

        // ---- phase A: poll full h (tag >= t) into hsmA ----
        if (tid < 128) {
            const int e = tid * 4;
            u64 v0, v1, v2, v3;
            for (;;) {
                v0 = tag_ld(&hbuf[e + 0]);
                v1 = tag_ld(&hbuf[e + 1]);
                v2 = tag_ld(&hbuf[e + 2]);
                v3 = tag_ld(&hbuf[e + 3]);
                if ((unsigned)(v0 >> 32) >= ta && (unsigned)(v1 >> 32) >= ta &&
                    (unsigned)(v2 >> 32) >= ta && (unsigned)(v3 >> 32) >= ta)
                    break;
            }
            float* p = &hsmA[(e >> 5) * 33 + (e & 31)];
            p[0] = unpackv(v0); p[1] = unpackv(v1);
            p[2] = unpackv(v2); p[3] = unpackv(v3);
        }
        __syncthreads();   // bar1: hsmA ready (also covers prev hsmB reuse)

        float az = 0.f, ar = 0.f;
#pragma unroll
        for (int j = 0; j < 32; ++j) {
            float hj = hsmA[cg * 33 + j];
            az = fmaf(uzw[j], hj, az);
            ar = fmaf(urw[j], hj, ar);
        }
#pragma unroll
        for (int mk = 8; mk; mk >>= 1) {
            az += __shfl_xor(az, mk);
            ar += __shfl_xor(ar, mk);
        }
        const float hrow = hsmA[b * 33 + r];   // h[g] (padded index)
        const float zz = 1.f / (1.f + __expf(-(ezc + az + bzv)));
        const float rr = 1.f / (1.f + __expf(-(erc + ar + brv)));
        if (cg == 0) tag_st(&rhbuf[g], packtv(rr * hrow, tb));
        // no barrier: rhbuf store-ack drains under the phase-B poll below

        // ---- phase B: poll full r*h (tag >= t+1) into hsmB ----
        if (tid < 128) {
            const int e = tid * 4;
            u64 v0, v1, v2, v3;
            for (;;) {
                v0 = tag_ld(&rhbuf[e + 0]);
                v1 = tag_ld(&rhbuf[e + 1]);
                v2 = tag_ld(&rhbuf[e + 2]);
                v3 = tag_ld(&rhbuf[e + 3]);
                if ((unsigned)(v0 >> 32) >= tb && (unsigned)(v1 >> 32) >= tb &&
                    (unsigned)(v2 >> 32) >= tb && (unsigned)(v3 >> 32) >= tb)
                    break;
            }
            float* p = &hsmB[(e >> 5) * 33 + (e & 31)];
            p[0] = unpackv(v0); p[1] = unpackv(v1);
            p[2] = unpackv(v2); p[3] = unpackv(v3);
        }
        __syncthreads();   // bar2: hsmB ready (also covers hsmA reuse)

        float ah = 0.f;
#pragma unroll
        for (int j = 0; j < 32; ++j) {
            float xj = hsmB[cg * 33 + j];
            ah = fmaf(uw[j], xj, ah);
        }
#pragma unroll
        for (int mk = 8; mk; mk >>= 1) ah += __shfl_xor(ah, mk);

        const float hxh  = ftanh(ehc + ah + bhv);
        const float hnew = hrow * zz + (1.f - zz) * hxh;
        if (cg == 0) {
            tag_st(&hbuf[g], packtv(hnew, tb));   // next step's input, tag t+1
            outH[(size_t)t * D + g] = hnew;       // f32 hiddens output
        }
        // no barrier: hbuf/outH acks drain under next step's phase-A poll

        ezc = pz; erc = pr; ehc = ph;
    }
}

// ---------------------------------------------------------------------------
// logits GEMM (MFMA bf16): C[2048][32000] = hs * wy^T + by, f32 out.
// 128x128 tile, BK=64, 4 waves (2x2), 64x64/wave; f32->bf16 during staging.
// C/D layout (verified): col = lane&15, row = (lane>>4)*4 + q.
// ---------------------------------------------------------------------------
#define GBM 128
#define GBN 128
#define GBK 64

__global__ __launch_bounds__(256) void gemm_logits(
    const float* __restrict__ A,   // hs f32 [2048][512]
    const float* __restrict__ B,   // wy f32 [32000][512]
    const float* __restrict__ BY,  // by f32 [32000]
    float* __restrict__ C)         // logits f32 [2048][32000]
{
    __shared__ __align__(16) u16 As[GBM * GBK];
    __shared__ __align__(16) u16 Bs[GBN * GBK];

    const int tid = threadIdx.x;
    const int wv = tid >> 6, lane = tid & 63;
    const int lr = lane & 15, lg = lane >> 4;
    const int bm = blockIdx.y, bn = blockIdx.x;
    const int wm = (wv >> 1) * 64, wn = (wv & 1) * 64;

    const int srow = tid >> 3;        // 0..31 (row within 32-row pass)
    const int scol = (tid & 7) * 8;   // 0..56

    f32x4 acc[4][4] = {};

    for (int kt = 0; kt < D; kt += GBK) {
        __syncthreads();
#pragma unroll
        for (int p = 0; p < 4; ++p) {
            const int row = p * 32 + srow;
            f32x4 a0 = *(const f32x4*)&A[(size_t)(bm * GBM + row) * D + kt + scol];
            f32x4 a1 = *(const f32x4*)&A[(size_t)(bm * GBM + row) * D + kt + scol + 4];
            f32x4 b0 = *(const f32x4*)&B[(size_t)(bn * GBN + row) * D + kt + scol];
            f32x4 b1 = *(const f32x4*)&B[(size_t)(bn * GBN + row) * D + kt + scol + 4];
            us8 oa, ob;
#pragma unroll
            for (int q = 0; q < 4; ++q) {
                oa[q] = f2bf(a0[q]); oa[4 + q] = f2bf(a1[q]);
                ob[q] = f2bf(b0[q]); ob[4 + q] = f2bf(b1[q]);
            }
            *(us8*)&As[row * GBK + scol] = oa;
            *(us8*)&Bs[row * GBK + scol] = ob;
        }
        __syncthreads();
#pragma unroll
        for (int kk = 0; kk < 2; ++kk) {
            bf16x8 af[4], bfr[4];
#pragma unroll
            for (int mi = 0; mi < 4; ++mi)
                af[mi] = *(const bf16x8*)&As[(wm + mi * 16 + lr) * GBK + kk * 32 + lg * 8];
#pragma unroll
            for (int ni = 0; ni < 4; ++ni)
                bfr[ni] = *(const bf16x8*)&Bs[(wn + ni * 16 + lr) * GBK + kk * 32 + lg * 8];
#pragma unroll
            for (int mi = 0; mi < 4; ++mi)
#pragma unroll
                for (int ni = 0; ni < 4; ++ni)
                    acc[mi][ni] = __builtin_amdgcn_mfma_f32_16x16x32_bf16(
                        af[mi], bfr[ni], acc[mi][ni], 0, 0, 0);
        }
    }

#pragma unroll
    for (int ni = 0; ni < 4; ++ni) {
        const int n = bn * GBN + wn + ni * 16 + lr;
        const float byv = BY[n];
#pragma unroll
        for (int mi = 0; mi < 4; ++mi) {
#pragma unroll
            for (int q = 0; q < 4; ++q) {
                const int m = bm * GBM + wm + mi * 16 + lg * 4 + q;
                C[(size_t)m * VOCAB + n] = acc[mi][ni][q] + byv;
            }
        }
    }
}

// ---------------------------------------------------------------------------
// in-place log-softmax per row (f32); logits tiny (|x|<=7) so no max pass.
// ---------------------------------------------------------------------------
__global__ __launch_bounds__(256) void logsoftmax_kernel(float* __restrict__ C)
{
    const int m = blockIdx.x;
    float* row = C + (size_t)m * VOCAB;
    const int tid = threadIdx.x;

    float s = 0.f;
    for (int v = tid; v < VOCAB / 4; v += 256) {
        f32x4 x = *(const f32x4*)&row[v * 4];
        s += __expf(x[0]) + __expf(x[1]) + __expf(x[2]) + __expf(x[3]);
    }
#pragma unroll
    for (int mk = 32; mk; mk >>= 1) s += __shfl_xor(s, mk);
    __shared__ float red[4];
    if ((tid & 63) == 0) red[tid >> 6] = s;
    __syncthreads();
    const float lse = __logf(red[0] + red[1] + red[2] + red[3]);

    for (int v = tid; v < VOCAB / 4; v += 256) {
        f32x4 x = *(const f32x4*)&row[v * 4];
        x[0] -= lse; x[1] -= lse; x[2] -= lse; x[3] -= lse;
        *(f32x4*)&row[v * 4] = x;
    }
}

extern "C" void kernel_launch(void* const* d_in, const int* in_sizes, int n_in,
                              void* d_out, int out_size, void* d_ws, size_t ws_size,
                              hipStream_t stream)
{
    const int*   X  = (const int*)d_in[0];
    const float* wz = (const float*)d_in[1];
    const float* uz = (const float*)d_in[2];
    const float* w  = (const float*)d_in[3];
    const float* u  = (const float*)d_in[4];
    const float* wr = (const float*)d_in[5];
    const float* ur = (const float*)d_in[6];
    const float* wy = (const float*)d_in[7];
    const float* bz = (const float*)d_in[8];
    const float* br = (const float*)d_in[9];
    const float* bh = (const float*)d_in[10];
    const float* by = (const float*)d_in[11];

    float* out  = (float*)d_out;                     // outs f32 [2048][32000]
    float* outH = out + (size_t)SEQ * VOCAB;         // hiddens f32 [2048][512]

    // cross-block scratch: prefer d_ws; fall back to logits head (overwritten
    // by the GEMM later) if the workspace is unexpectedly small.
    char* scratch = (ws_size >= 8192) ? (char*)d_ws : (char*)d_out;
    u64* hbuf  = (u64*)scratch;                    // 4KB tagged h
    u64* rhbuf = (u64*)(scratch + 4096);           // 4KB tagged r*h

    init_scratch<<<1, STPB, 0, stream>>>(hbuf, rhbuf);

    scan_kernel<<<NB, STPB, 0, stream>>>(X, wz, uz, w, u, wr, ur, bz, br, bh,
                                         hbuf, rhbuf, outH);

    dim3 ggrid(VOCAB / GBN, SEQ / GBM);            // (250, 16)
    gemm_logits<<<ggrid, 256, 0, stream>>>(outH, wy, by, out);

    logsoftmax_kernel<<<SEQ, 256, 0, stream>>>(out);
}

// Round 9
// 7261.071 us; speedup vs baseline: 1.1553x; 1.1553x over previous
//
#include <hip/hip_runtime.h>
#include <math.h>

typedef unsigned short u16;
typedef unsigned long long u64;
typedef unsigned short us8 __attribute__((ext_vector_type(8)));
typedef short bf16x8 __attribute__((ext_vector_type(8)));
typedef float f32x4 __attribute__((ext_vector_type(4)));

#define D       512
#define SEQ     2048
#define VOCAB   32000
#define NB      16      // scan blocks
#define RPB     32      // rows per block (512/16)
#define STPB    512     // scan threads per block
#define PBSTR   576     // u64 per block per step: 512 partials + 32 zh + 32 oz
#define PBTOT   (2 * NB * PBSTR)   // parity-double-buffered

__device__ __forceinline__ u16 f2bf(float f) {   // round-to-nearest-even
    union { float f; unsigned i; } x; x.f = f;
    unsigned r = x.i + 0x7fff + ((x.i >> 16) & 1);
    return (u16)(r >> 16);
}

// tagged-value exchange: one 8B atom = (step_tag << 32) | f32 bits.
// relaxed agent-scope => LLC-coherent, no cache maintenance; tag+value are
// single-copy atomic so the poll hit IS the data read.
__device__ __forceinline__ u64 tag_ld(const u64* p) {
    return __hip_atomic_load(p, __ATOMIC_RELAXED, __HIP_MEMORY_SCOPE_AGENT);
}
__device__ __forceinline__ void tag_st(u64* p, u64 v) {
    __hip_atomic_store(p, v, __ATOMIC_RELAXED, __HIP_MEMORY_SCOPE_AGENT);
}
__device__ __forceinline__ u64 packtv(float f, unsigned tag) {
    union { float f; unsigned i; } x; x.f = f;
    return ((u64)tag << 32) | (u64)x.i;
}
__device__ __forceinline__ float unpackv(u64 v) {
    union { unsigned i; float f; } x; x.i = (unsigned)v;
    return x.f;
}
// fast tanh: 1 - 2/(1+e^{2x}); exact at +-inf, ~1e-6 rel err
__device__ __forceinline__ float ftanh(float x) {
    return 1.f - 2.f / (1.f + __expf(2.f * x));
}
// LDS-only barrier: orders ds ops across the block WITHOUT draining vmcnt,
// so global-store acks keep flowing under the subsequent poll (HK pattern).
__device__ __forceinline__ void bar_lds() {
    asm volatile("s_waitcnt lgkmcnt(0)" ::: "memory");
    __builtin_amdgcn_s_barrier();
}

// ---------------------------------------------------------------------------
// zero the exchange buffer (tags=0 < first tag 1); runs every call/replay.
// ---------------------------------------------------------------------------
__global__ void init_scratch(u64* __restrict__ pbuf)
{
    const int t = blockIdx.x * blockDim.x + threadIdx.x;
    if (t < PBTOT) pbuf[t] = 0ull;
}

// ---------------------------------------------------------------------------
// Single-exchange persistent GRU scan. Block b owns ROWS [32b,32b+32) of
// uz,ur and COLUMNS [32b,32b+32) of u. Per step t (tag tt=t+1, parity tt&1):
//   1. z_g,r_g from full h (local, LDS hsm); rhsm[g] = r_g*h_g   [bar_lds]
//   2. P_b[i] = sum_{j in cols_b} u[i][j]*rhsm[j] for ALL i; publish
//      {P_b, z_g*h_g, 1-z_g} tagged tt (acks drain under the poll)
//   3. poll all 16 blocks' atoms tagged tt; every block redundantly computes
//      the FULL h_{t+1} (bitwise identical) -> hsm               [bar_lds]
// No h broadcast. Parity double-buffer kills the overwrite race: writing
// tag t+3 to a slot requires every block consumed tag t+1 (proof: t+3 write
// needs all t+2 reads; a block's t+2 write follows its t+1 reads).
// ---------------------------------------------------------------------------
__global__ __launch_bounds__(STPB, 2) void scan_kernel(
    const int* __restrict__ X,
    const float* __restrict__ WZ, const float* __restrict__ UZ,
    const float* __restrict__ W,  const float* __restrict__ U,
    const float* __restrict__ WR, const float* __restrict__ UR,
    const float* __restrict__ BZ, const float* __restrict__ BR,
    const float* __restrict__ BH,
    u64* __restrict__ pbuf,
    float* __restrict__ outH)
{
    __shared__ int   idxsm[SEQ];
    __shared__ float hsm[(D / 32) * 33];   // padded full h (stride 33)
    __shared__ float rhsm[RPB];            // r*h for own rows

    const int tid = threadIdx.x, b = blockIdx.x;
    const int r  = tid >> 4;          // 0..31 local row (z/r phase)
    const int cg = tid & 15;          // 0..15 column group (z/r phase)
    const int c0 = cg * 32;
    const int g  = b * RPB + r;       // own global row
    const int i  = tid;               // output row this thread owns (reduce)

    for (int k = tid; k < SEQ; k += STPB) idxsm[k] = X[k];

    // weights: uz,ur row slices (32 each) + u column slice (32) = 96 VGPR
    float uzw[32], urw[32], ucol[32];
#pragma unroll
    for (int j = 0; j < 32; j += 4) {
        f32x4 vz = *(const f32x4*)&UZ[(size_t)g * D + c0 + j];
        f32x4 vr = *(const f32x4*)&UR[(size_t)g * D + c0 + j];
        f32x4 vu = *(const f32x4*)&U [(size_t)i * D + b * RPB + j];
#pragma unroll
        for (int q = 0; q < 4; ++q) {
            uzw[j + q]  = vz[q];
            urw[j + q]  = vr[q];
            ucol[j + q] = vu[q];
        }
    }
    const float bzv = BZ[g], brv = BR[g], bhv = BH[i];

    hsm[(i >> 5) * 33 + (i & 31)] = 0.f;   // h0 = 0
    __syncthreads();                        // full barrier once (setup)

    // embedding pipeline: z,r at own row g; h-gate at own output row i
    const int i0 = idxsm[0];
    float ezc = WZ[(size_t)i0 * D + g];
    float erc = WR[(size_t)i0 * D + g];
    float ehc = W [(size_t)i0 * D + i];

    float hprev = 0.f;                      // deferred outH value
    u64* const pb0 = pbuf;                  // parity 0
    u64* const pb1 = pbuf + NB * PBSTR;     // parity 1

#pragma unroll 1
    for (int t = 0; t < SEQ; ++t) {
        // deferred outH store (h_t computed last iteration); ack drains
        // under this step's poll, never at a barrier.
        if (t > 0 && (i >> 5) == b) outH[(size_t)(t - 1) * D + i] = hprev;

        const int tn = (t + 1 < SEQ) ? t + 1 : t;
        const int in_ = idxsm[tn];
        const float pz = WZ[(size_t)in_ * D + g];
        const float pr = WR[(size_t)in_ * D + g];
        const float ph = W [(size_t)in_ * D + i];
        const unsigned tt = (unsigned)t + 1u;
        u64* const pb = (tt & 1u) ? pb1 : pb0;

        // ---- 1. z,r for own rows from full h (LDS) ----
        float az = 0.f, ar = 0.f;
#pragma unroll
        for (int j = 0; j < 32; ++j) {
            float hj = hsm[cg * 33 + j];
            az = fmaf(uzw[j], hj, az);
            ar = fmaf(urw[j], hj, ar);
        }
#pragma unroll
        for (int mk = 8; mk; mk >>= 1) {
            az += __shfl_xor(az, mk);
            ar += __shfl_xor(ar, mk);
        }
        const float hrow = hsm[b * 33 + r];            // h_t[g]
        const float zz = 1.f / (1.f + __expf(-(ezc + az + bzv)));
        const float rr = 1.f / (1.f + __expf(-(erc + ar + brv)));
        if (cg == 0) rhsm[r] = rr * hrow;
        bar_lds();                                     // rhsm ready (LDS only)

        // ---- 2. partial for ALL outputs over own 32 columns; publish ----
        float P = 0.f;
#pragma unroll
        for (int jl = 0; jl < 32; ++jl) P = fmaf(ucol[jl], rhsm[jl], P);
        tag_st(&pb[b * PBSTR + i], packtv(P, tt));
        if (cg == 0) {
            tag_st(&pb[b * PBSTR + 512 + r], packtv(zz * hrow, tt));
            tag_st(&pb[b * PBSTR + 544 + r], packtv(1.f - zz, tt));
        }

        // ---- 3. poll all contributions for output row i ----
        u64 vP[NB], vzh, voz;
        const int ow = i >> 5, il = i & 31;            // owner block of row i
        for (;;) {
            bool ok = true;
#pragma unroll
            for (int bb = 0; bb < NB; ++bb) {
                vP[bb] = tag_ld(&pb[bb * PBSTR + i]);
                ok &= ((unsigned)(vP[bb] >> 32) >= tt);
            }
            vzh = tag_ld(&pb[ow * PBSTR + 512 + il]);
            voz = tag_ld(&pb[ow * PBSTR + 544 + il]);
            ok &= ((unsigned)(vzh >> 32) >= tt) & ((unsigned)(voz >> 32) >= tt);
            if (ok) break;
        }
        float s = 0.f;
#pragma unroll
        for (int bb = 0; bb < NB; ++bb) s += unpackv(vP[bb]);
        const float hxh  = ftanh(ehc + s + bhv);
        const float hnew = unpackv(vzh) + unpackv(voz) * hxh;  // full h_{t+1}

        hsm[(i >> 5) * 33 + (i & 31)] = hnew;          // redundant, identical
        hprev = hnew;
        bar_lds();                                     // hsm ready (LDS only)

        ezc = pz; erc = pr; ehc = ph;
    }
    // final outH row
    if ((i >> 5) == b) outH[(size_t)(SEQ - 1) * D + i] = hprev;
}

// ---------------------------------------------------------------------------
// logits GEMM (MFMA bf16): C[2048][32000] = hs * wy^T + by, f32 out.
// 128x128 tile, BK=64, 4 waves (2x2), 64x64/wave; f32->bf16 during staging.
// C/D layout (verified): col = lane&15, row = (lane>>4)*4 + q.
// ---------------------------------------------------------------------------
#define GBM 128
#define GBN 128
#define GBK 64

__global__ __launch_bounds__(256) void gemm_logits(
    const float* __restrict__ A,   // hs f32 [2048][512]
    const float* __restrict__ B,   // wy f32 [32000][512]
    const float* __restrict__ BY,  // by f32 [32000]
    float* __restrict__ C)         // logits f32 [2048][32000]
{
    __shared__ __align__(16) u16 As[GBM * GBK];
    __shared__ __align__(16) u16 Bs[GBN * GBK];

    const int tid = threadIdx.x;
    const int wv = tid >> 6, lane = tid & 63;
    const int lr = lane & 15, lg = lane >> 4;
    const int bm = blockIdx.y, bn = blockIdx.x;
    const int wm = (wv >> 1) * 64, wn = (wv & 1) * 64;

    const int srow = tid >> 3;        // 0..31 (row within 32-row pass)
    const int scol = (tid & 7) * 8;   // 0..56

    f32x4 acc[4][4] = {};

    for (int kt = 0; kt < D; kt += GBK) {
        __syncthreads();
#pragma unroll
        for (int p = 0; p < 4; ++p) {
            const int row = p * 32 + srow;
            f32x4 a0 = *(const f32x4*)&A[(size_t)(bm * GBM + row) * D + kt + scol];
            f32x4 a1 = *(const f32x4*)&A[(size_t)(bm * GBM + row) * D + kt + scol + 4];
            f32x4 b0 = *(const f32x4*)&B[(size_t)(bn * GBN + row) * D + kt + scol];
            f32x4 b1 = *(const f32x4*)&B[(size_t)(bn * GBN + row) * D + kt + scol + 4];
            us8 oa, ob;
#pragma unroll
            for (int q = 0; q < 4; ++q) {
                oa[q] = f2bf(a0[q]); oa[4 + q] = f2bf(a1[q]);
                ob[q] = f2bf(b0[q]); ob[4 + q] = f2bf(b1[q]);
            }
            *(us8*)&As[row * GBK + scol] = oa;
            *(us8*)&Bs[row * GBK + scol] = ob;
        }
        __syncthreads();
#pragma unroll
        for (int kk = 0; kk < 2; ++kk) {
            bf16x8 af[4], bfr[4];
#pragma unroll
            for (int mi = 0; mi < 4; ++mi)
                af[mi] = *(const bf16x8*)&As[(wm + mi * 16 + lr) * GBK + kk * 32 + lg * 8];
#pragma unroll
            for (int ni = 0; ni < 4; ++ni)
                bfr[ni] = *(const bf16x8*)&Bs[(wn + ni * 16 + lr) * GBK + kk * 32 + lg * 8];
#pragma unroll
            for (int mi = 0; mi < 4; ++mi)
#pragma unroll
                for (int ni = 0; ni < 4; ++ni)
                    acc[mi][ni] = __builtin_amdgcn_mfma_f32_16x16x32_bf16(
                        af[mi], bfr[ni], acc[mi][ni], 0, 0, 0);
        }
    }

#pragma unroll
    for (int ni = 0; ni < 4; ++ni) {
        const int n = bn * GBN + wn + ni * 16 + lr;
        const float byv = BY[n];
#pragma unroll
        for (int mi = 0; mi < 4; ++mi) {
#pragma unroll
            for (int q = 0; q < 4; ++q) {
                const int m = bm * GBM + wm + mi * 16 + lg * 4 + q;
                C[(size_t)m * VOCAB + n] = acc[mi][ni][q] + byv;
            }
        }
    }
}

// ---------------------------------------------------------------------------
// in-place log-softmax per row (f32); logits tiny (|x|<=7) so no max pass.
// ---------------------------------------------------------------------------
__global__ __launch_bounds__(256) void logsoftmax_kernel(float* __restrict__ C)
{
    const int m = blockIdx.x;
    float* row = C + (size_t)m * VOCAB;
    const int tid = threadIdx.x;

    float s = 0.f;
    for (int v = tid; v < VOCAB / 4; v += 256) {
        f32x4 x = *(const f32x4*)&row[v * 4];
        s += __expf(x[0]) + __expf(x[1]) + __expf(x[2]) + __expf(x[3]);
    }
#pragma unroll
    for (int mk = 32; mk; mk >>= 1) s += __shfl_xor(s, mk);
    __shared__ float red[4];
    if ((tid & 63) == 0) red[tid >> 6] = s;
    __syncthreads();
    const float lse = __logf(red[0] + red[1] + red[2] + red[3]);

    for (int v = tid; v < VOCAB / 4; v += 256) {
        f32x4 x = *(const f32x4*)&row[v * 4];
        x[0] -= lse; x[1] -= lse; x[2] -= lse; x[3] -= lse;
        *(f32x4*)&row[v * 4] = x;
    }
}

extern "C" void kernel_launch(void* const* d_in, const int* in_sizes, int n_in,
                              void* d_out, int out_size, void* d_ws, size_t ws_size,
                              hipStream_t stream)
{
    const int*   X  = (const int*)d_in[0];
    const float* wz = (const float*)d_in[1];
    const float* uz = (const float*)d_in[2];
    const float* w  = (const float*)d_in[3];
    const float* u  = (const float*)d_in[4];
    const float* wr = (const float*)d_in[5];
    const float* ur = (const float*)d_in[6];
    const float* wy = (const float*)d_in[7];
    const float* bz = (const float*)d_in[8];
    const float* br = (const float*)d_in[9];
    const float* bh = (const float*)d_in[10];
    const float* by = (const float*)d_in[11];

    float* out  = (float*)d_out;                     // outs f32 [2048][32000]
    float* outH = out + (size_t)SEQ * VOCAB;         // hiddens f32 [2048][512]

    // exchange buffer (147,456 B): prefer d_ws; else logits head (the GEMM,
    // stream-ordered after the scan, overwrites it with real logits).
    const size_t pbytes = (size_t)PBTOT * 8;
    u64* pbuf = (ws_size >= pbytes) ? (u64*)d_ws : (u64*)d_out;

    init_scratch<<<(PBTOT + STPB - 1) / STPB, STPB, 0, stream>>>(pbuf);

    scan_kernel<<<NB, STPB, 0, stream>>>(X, wz, uz, w, u, wr, ur, bz, br, bh,
                                         pbuf, outH);

    dim3 ggrid(VOCAB / GBN, SEQ / GBM);            // (250, 16)
    gemm_logits<<<ggrid, 256, 0, stream>>>(outH, wy, by, out);

    logsoftmax_kernel<<<SEQ, 256, 0, stream>>>(out);
}

// Round 10
// 7013.048 us; speedup vs baseline: 1.1961x; 1.0354x over previous
//
#include <hip/hip_runtime.h>
#include <math.h>

typedef unsigned short u16;
typedef unsigned long long u64;
typedef long long s64;
typedef unsigned short us8 __attribute__((ext_vector_type(8)));
typedef short bf16x8 __attribute__((ext_vector_type(8)));
typedef float f32x4 __attribute__((ext_vector_type(4)));

#define D       512
#define SEQ     2048
#define VOCAB   32000
#define NB      16      // scan blocks
#define RPB     32      // rows per block (512/16)
#define STPB    512     // scan threads per block

// acc layout: [SEQ][D][4] u64 = {P packed-add, zh tagged, oz tagged, pad}
// one 32B group per (step,row) -> consumer polls ONE cacheline.
#define ACCN    ((size_t)SEQ * D * 4)
#define ACCB    (ACCN * 8)              // 32 MB

// fixed-point packing for the LLC-side reduction
#define FXSCALE 1073741824.0f           // 2^30
#define BIAS1   (1ll << 51)             // per-add bias (16 adds -> 2^55 exact)
#define SUMBIAS (1ll << 55)
#define MASK56  ((1ull << 56) - 1)
#define COUNT1  (1ull << 56)

__device__ __forceinline__ u16 f2bf(float f) {   // round-to-nearest-even
    union { float f; unsigned i; } x; x.f = f;
    unsigned r = x.i + 0x7fff + ((x.i >> 16) & 1);
    return (u16)(r >> 16);
}

// relaxed agent-scope (LLC-coherent) primitives — no cache maintenance.
__device__ __forceinline__ u64 tag_ld(const u64* p) {
    return __hip_atomic_load(p, __ATOMIC_RELAXED, __HIP_MEMORY_SCOPE_AGENT);
}
__device__ __forceinline__ void tag_st(u64* p, u64 v) {
    __hip_atomic_store(p, v, __ATOMIC_RELAXED, __HIP_MEMORY_SCOPE_AGENT);
}
__device__ __forceinline__ void acc_add(u64* p, u64 v) {
    (void)__hip_atomic_fetch_add(p, v, __ATOMIC_RELAXED, __HIP_MEMORY_SCOPE_AGENT);
}
__device__ __forceinline__ u64 packtv(float f, unsigned tag) {
    union { float f; unsigned i; } x; x.f = f;
    return ((u64)tag << 32) | (u64)x.i;
}
__device__ __forceinline__ float unpackv(u64 v) {
    union { unsigned i; float f; } x; x.i = (unsigned)v;
    return x.f;
}
// fast tanh: 1 - 2/(1+e^{2x}); exact at +-inf, ~1e-6 rel err
__device__ __forceinline__ float ftanh(float x) {
    return 1.f - 2.f / (1.f + __expf(2.f * x));
}
// LDS-only barrier: orders ds ops across the block WITHOUT draining vmcnt,
// so global stores/adds keep flying under the subsequent poll.
__device__ __forceinline__ void bar_lds() {
    asm volatile("s_waitcnt lgkmcnt(0)" ::: "memory");
    __builtin_amdgcn_s_barrier();
}

// ---------------------------------------------------------------------------
// zero the 32MB accumulator arena; runs every call/replay (graph-safe).
// ---------------------------------------------------------------------------
__global__ void init_scratch(u64* __restrict__ acc)
{
    const size_t stride = (size_t)gridDim.x * blockDim.x;
    for (size_t k = blockIdx.x * (size_t)blockDim.x + threadIdx.x; k < ACCN;
         k += stride)
        acc[k] = 0ull;
}

// ---------------------------------------------------------------------------
// Packed-add persistent GRU scan. Block b owns ROWS [32b,32b+32) of uz,ur
// and COLUMNS [32b,32b+32) of u. Per step t (tag tt=t+1):
//   1. z_g,r_g from full h (local LDS); rhsm = r*h          [bar_lds]
//   2. P_b[i] over own 32 cols for ALL i; fetch-add packed {count|fx} into
//      acc[t][i][0]; owner rows tag-store zh,oz into [1],[2]
//   3. poll OWN line until count==16 & tags==tt; LLC already summed the
//      partials -> unpack, tanh, h_{t+1}; write hsm (all blocks identical)
//      [bar_lds]
// Fresh accumulator slot per step: no reuse, no reset, no parity races.
// ---------------------------------------------------------------------------
__global__ __launch_bounds__(STPB, 2) void scan_kernel(
    const int* __restrict__ X,
    const float* __restrict__ WZ, const float* __restrict__ UZ,
    const float* __restrict__ W,  const float* __restrict__ U,
    const float* __restrict__ WR, const float* __restrict__ UR,
    const float* __restrict__ BZ, const float* __restrict__ BR,
    const float* __restrict__ BH,
    u64* __restrict__ acc,
    float* __restrict__ outH)
{
    __shared__ int   idxsm[SEQ];
    __shared__ float hsm[(D / 32) * 33];   // padded full h (stride 33)
    __shared__ float rhsm[RPB];            // r*h for own rows

    const int tid = threadIdx.x, b = blockIdx.x;
    const int r  = tid >> 4;          // 0..31 local row (z/r phase)
    const int cg = tid & 15;          // 0..15 column group (z/r phase)
    const int c0 = cg * 32;
    const int g  = b * RPB + r;       // own global row
    const int i  = tid;               // output row this thread owns

    for (int k = tid; k < SEQ; k += STPB) idxsm[k] = X[k];

    // weights: uz,ur row slices + u column slice = 96 VGPR
    float uzw[32], urw[32], ucol[32];
#pragma unroll
    for (int j = 0; j < 32; j += 4) {
        f32x4 vz = *(const f32x4*)&UZ[(size_t)g * D + c0 + j];
        f32x4 vr = *(const f32x4*)&UR[(size_t)g * D + c0 + j];
        f32x4 vu = *(const f32x4*)&U [(size_t)i * D + b * RPB + j];
#pragma unroll
        for (int q = 0; q < 4; ++q) {
            uzw[j + q]  = vz[q];
            urw[j + q]  = vr[q];
            ucol[j + q] = vu[q];
        }
    }
    const float bzv = BZ[g], brv = BR[g], bhv = BH[i];

    hsm[(i >> 5) * 33 + (i & 31)] = 0.f;   // h0 = 0
    __syncthreads();                        // setup barrier (once)

    // embedding pipeline: z,r at own row g; h-gate at own output row i
    const int i0 = idxsm[0];
    float ezc = WZ[(size_t)i0 * D + g];
    float erc = WR[(size_t)i0 * D + g];
    float ehc = W [(size_t)i0 * D + i];

#pragma unroll 1
    for (int t = 0; t < SEQ; ++t) {
        const int tn = (t + 1 < SEQ) ? t + 1 : t;
        const int in_ = idxsm[tn];
        const float pz = WZ[(size_t)in_ * D + g];
        const float pr = WR[(size_t)in_ * D + g];
        const float ph = W [(size_t)in_ * D + i];
        const unsigned tt = (unsigned)t + 1u;
        u64* const line = acc + ((size_t)t * D + i) * 4;

        // ---- 1. z,r for own rows from full h (LDS) ----
        float az = 0.f, ar = 0.f;
#pragma unroll
        for (int j = 0; j < 32; ++j) {
            float hj = hsm[cg * 33 + j];
            az = fmaf(uzw[j], hj, az);
            ar = fmaf(urw[j], hj, ar);
        }
#pragma unroll
        for (int mk = 8; mk; mk >>= 1) {
            az += __shfl_xor(az, mk);
            ar += __shfl_xor(ar, mk);
        }
        const float hrow = hsm[b * 33 + r];            // h_t[g]
        const float zz = 1.f / (1.f + __expf(-(ezc + az + bzv)));
        const float rr = 1.f / (1.f + __expf(-(erc + ar + brv)));
        if (cg == 0) rhsm[r] = rr * hrow;
        bar_lds();                                     // rhsm ready

        // ---- 2. partial over own 32 columns; LLC-side reduction ----
        float P = 0.f;
#pragma unroll
        for (int jl = 0; jl < 32; ++jl) P = fmaf(ucol[jl], rhsm[jl], P);
        acc_add(line + 0 - (size_t)i * 4 + ((size_t)i) * 4,   // = line+0
                COUNT1 + (u64)(BIAS1 + (s64)(P * FXSCALE)));
        if (cg == 0) {
            u64* oline = acc + ((size_t)t * D + g) * 4;
            tag_st(oline + 1, packtv(zz * hrow, tt));
            tag_st(oline + 2, packtv(1.f - zz, tt));
        }

        // ---- 3. poll OWN 32B line: count==16 and both tags ----
        u64 v0, v1, v2;
        for (;;) {
            v0 = tag_ld(line + 0);
            v1 = tag_ld(line + 1);
            v2 = tag_ld(line + 2);
            if ((v0 >> 56) == 16ull &&
                (unsigned)(v1 >> 32) == tt && (unsigned)(v2 >> 32) == tt)
                break;
        }
        const s64 fx = (s64)(v0 & MASK56) - SUMBIAS;   // exact 16-way sum
        const float s = (float)fx * (1.0f / FXSCALE);
        const float hxh  = ftanh(ehc + s + bhv);
        const float hnew = unpackv(v1) + unpackv(v2) * hxh;

        hsm[(i >> 5) * 33 + (i & 31)] = hnew;          // identical in all blocks
        if ((i >> 5) == b) outH[(size_t)t * D + i] = hnew;  // fire-and-forget
        bar_lds();                                     // hsm ready

        ezc = pz; erc = pr; ehc = ph;
    }
}

// ---------------------------------------------------------------------------
// logits GEMM (MFMA bf16): C[2048][32000] = hs * wy^T + by, f32 out.
// 128x128 tile, BK=64, 4 waves (2x2), 64x64/wave; f32->bf16 during staging.
// ---------------------------------------------------------------------------
#define GBM 128
#define GBN 128
#define GBK 64

__global__ __launch_bounds__(256) void gemm_logits(
    const float* __restrict__ A,   // hs f32 [2048][512]
    const float* __restrict__ B,   // wy f32 [32000][512]
    const float* __restrict__ BY,  // by f32 [32000]
    float* __restrict__ C)         // logits f32 [2048][32000]
{
    __shared__ __align__(16) u16 As[GBM * GBK];
    __shared__ __align__(16) u16 Bs[GBN * GBK];

    const int tid = threadIdx.x;
    const int wv = tid >> 6, lane = tid & 63;
    const int lr = lane & 15, lg = lane >> 4;
    const int bm = blockIdx.y, bn = blockIdx.x;
    const int wm = (wv >> 1) * 64, wn = (wv & 1) * 64;

    const int srow = tid >> 3;        // 0..31 (row within 32-row pass)
    const int scol = (tid & 7) * 8;   // 0..56

    f32x4 acc[4][4] = {};

    for (int kt = 0; kt < D; kt += GBK) {
        __syncthreads();
#pragma unroll
        for (int p = 0; p < 4; ++p) {
            const int row = p * 32 + srow;
            f32x4 a0 = *(const f32x4*)&A[(size_t)(bm * GBM + row) * D + kt + scol];
            f32x4 a1 = *(const f32x4*)&A[(size_t)(bm * GBM + row) * D + kt + scol + 4];
            f32x4 b0 = *(const f32x4*)&B[(size_t)(bn * GBN + row) * D + kt + scol];
            f32x4 b1 = *(const f32x4*)&B[(size_t)(bn * GBN + row) * D + kt + scol + 4];
            us8 oa, ob;
#pragma unroll
            for (int q = 0; q < 4; ++q) {
                oa[q] = f2bf(a0[q]); oa[4 + q] = f2bf(a1[q]);
                ob[q] = f2bf(b0[q]); ob[4 + q] = f2bf(b1[q]);
            }
            *(us8*)&As[row * GBK + scol] = oa;
            *(us8*)&Bs[row * GBK + scol] = ob;
        }
        __syncthreads();
#pragma unroll
        for (int kk = 0; kk < 2; ++kk) {
            bf16x8 af[4], bfr[4];
#pragma unroll
            for (int mi = 0; mi < 4; ++mi)
                af[mi] = *(const bf16x8*)&As[(wm + mi * 16 + lr) * GBK + kk * 32 + lg * 8];
#pragma unroll
            for (int ni = 0; ni < 4; ++ni)
                bfr[ni] = *(const bf16x8*)&Bs[(wn + ni * 16 + lr) * GBK + kk * 32 + lg * 8];
#pragma unroll
            for (int mi = 0; mi < 4; ++mi)
#pragma unroll
                for (int ni = 0; ni < 4; ++ni)
                    acc[mi][ni] = __builtin_amdgcn_mfma_f32_16x16x32_bf16(
                        af[mi], bfr[ni], acc[mi][ni], 0, 0, 0);
        }
    }

#pragma unroll
    for (int ni = 0; ni < 4; ++ni) {
        const int n = bn * GBN + wn + ni * 16 + lr;
        const float byv = BY[n];
#pragma unroll
        for (int mi = 0; mi < 4; ++mi) {
#pragma unroll
            for (int q = 0; q < 4; ++q) {
                const int m = bm * GBM + wm + mi * 16 + lg * 4 + q;
                C[(size_t)m * VOCAB + n] = acc[mi][ni][q] + byv;
            }
        }
    }
}

// ---------------------------------------------------------------------------
// in-place log-softmax per row (f32); logits tiny (|x|<=7) so no max pass.
// ---------------------------------------------------------------------------
__global__ __launch_bounds__(256) void logsoftmax_kernel(float* __restrict__ C)
{
    const int m = blockIdx.x;
    float* row = C + (size_t)m * VOCAB;
    const int tid = threadIdx.x;

    float s = 0.f;
    for (int v = tid; v < VOCAB / 4; v += 256) {
        f32x4 x = *(const f32x4*)&row[v * 4];
        s += __expf(x[0]) + __expf(x[1]) + __expf(x[2]) + __expf(x[3]);
    }
#pragma unroll
    for (int mk = 32; mk; mk >>= 1) s += __shfl_xor(s, mk);
    __shared__ float red[4];
    if ((tid & 63) == 0) red[tid >> 6] = s;
    __syncthreads();
    const float lse = __logf(red[0] + red[1] + red[2] + red[3]);

    for (int v = tid; v < VOCAB / 4; v += 256) {
        f32x4 x = *(const f32x4*)&row[v * 4];
        x[0] -= lse; x[1] -= lse; x[2] -= lse; x[3] -= lse;
        *(f32x4*)&row[v * 4] = x;
    }
}

extern "C" void kernel_launch(void* const* d_in, const int* in_sizes, int n_in,
                              void* d_out, int out_size, void* d_ws, size_t ws_size,
                              hipStream_t stream)
{
    const int*   X  = (const int*)d_in[0];
    const float* wz = (const float*)d_in[1];
    const float* uz = (const float*)d_in[2];
    const float* w  = (const float*)d_in[3];
    const float* u  = (const float*)d_in[4];
    const float* wr = (const float*)d_in[5];
    const float* ur = (const float*)d_in[6];
    const float* wy = (const float*)d_in[7];
    const float* bz = (const float*)d_in[8];
    const float* br = (const float*)d_in[9];
    const float* bh = (const float*)d_in[10];
    const float* by = (const float*)d_in[11];

    float* out  = (float*)d_out;                     // outs f32 [2048][32000]
    float* outH = out + (size_t)SEQ * VOCAB;         // hiddens f32 [2048][512]

    // 32MB accumulator arena: prefer d_ws; else logits head (overwritten by
    // the stream-ordered GEMM afterwards; logits region is 262MB).
    u64* acc = (ws_size >= ACCB) ? (u64*)d_ws : (u64*)d_out;

    init_scratch<<<2048, STPB, 0, stream>>>(acc);

    scan_kernel<<<NB, STPB, 0, stream>>>(X, wz, uz, w, u, wr, ur, bz, br, bh,
                                         acc, outH);

    dim3 ggrid(VOCAB / GBN, SEQ / GBM);            // (250, 16)
    gemm_logits<<<ggrid, 256, 0, stream>>>(outH, wy, by, out);

    logsoftmax_kernel<<<SEQ, 256, 0, stream>>>(out);
}